// Round 8
// baseline (515.110 us; speedup 1.0000x reference)
//
#include <hip/hip_runtime.h>
#include <hip/hip_bf16.h>
#include <math.h>

#define HWn 65536
#define Hh 256
#define Wd 256
#define Bb 2
#define Cc 64
#define NHh 8
#define HIDc 170
#define PXN 131072   // Bb * HWn

typedef __hip_bfloat16 bf16;
typedef __attribute__((ext_vector_type(8))) short short8;
typedef __attribute__((ext_vector_type(4))) short s16x4;
typedef __attribute__((ext_vector_type(4))) float f32x4;

__device__ inline float b2f(short u) {
    unsigned int x = ((unsigned int)(unsigned short)u) << 16;
    return __uint_as_float(x);
}
__device__ inline short f2b(float f) {
    __hip_bfloat16 h = __float2bfloat16(f);
    return *reinterpret_cast<short*>(&h);
}
__device__ __forceinline__ void zero8(short8& v) {
#pragma unroll
    for (int e = 0; e < 8; e++) v[e] = 0;
}
__device__ __forceinline__ float rfl(float x) {
    return __uint_as_float(__builtin_amdgcn_readfirstlane(__float_as_uint(x)));
}
// exact-to-1.5e-7 gelu via A&S 7.1.26 erf
__device__ __forceinline__ float gelu_f(float x) {
    float z = fabsf(x) * 0.70710678118654752f;
    float tt = __builtin_amdgcn_rcpf(fmaf(0.3275911f, z, 1.f));
    float p = tt * fmaf(tt, fmaf(tt, fmaf(tt, fmaf(tt, 1.061405429f, -1.453152027f),
                                          1.421413741f), -0.284496736f), 0.254829592f);
    float e = __expf(-z * z);
    float er = fmaf(-p, e, 1.f);
    er = copysignf(er, x);
    return 0.5f * x * (1.f + er);
}

// load one input row (8 ch) + left/right neighbors for lane-owned px t
__device__ __forceinline__ void dw_load_row(const bf16* __restrict__ base, int y, int t,
                                            float fl[8], float fc[8], float fr[8]) {
    const bf16* rp = base + (size_t)y * 2048 + (size_t)t * 8;
    short8 c8 = *reinterpret_cast<const short8*>(rp);
    short8 l8, r8;
    if (t > 0) l8 = *reinterpret_cast<const short8*>(rp - 8); else zero8(l8);
    if (t < 255) r8 = *reinterpret_cast<const short8*>(rp + 8); else zero8(r8);
#pragma unroll
    for (int e = 0; e < 8; e++) { fl[e] = b2f(l8[e]); fc[e] = b2f(c8[e]); fr[e] = b2f(r8[e]); }
}

// sliding-window dwconv: 4 output rows (y0..y0+3), 6 input-row loads
__device__ __forceinline__ void dw_quad(const bf16* __restrict__ base, int y0, int t,
                                        const float* wv, float acc[4][8]) {
#pragma unroll
    for (int r = 0; r < 4; r++)
#pragma unroll
        for (int e = 0; e < 8; e++) acc[r][e] = 0.f;
#pragma unroll
    for (int j = 0; j < 6; j++) {
        int yi = y0 - 1 + j;
        if (yi < 0 || yi > 255) continue;
        float fl[8], fc[8], fr[8];
        dw_load_row(base, yi, t, fl, fc, fr);
#pragma unroll
        for (int r = 0; r < 4; r++) {
            int dy = j - 1 - r;              // input - output row
            if (dy < -1 || dy > 1) continue;
            int wb = (dy + 1) * 3;
#pragma unroll
            for (int e = 0; e < 8; e++)
                acc[r][e] += wv[e * 9 + wb] * fl[e] + wv[e * 9 + wb + 1] * fc[e] +
                             wv[e * 9 + wb + 2] * fr[e];
        }
    }
}

// ---------- zero small scratch ----------
__global__ void zero_k(float* p, int n) {
    for (int i = threadIdx.x; i < n; i += 256) p[i] = 0.f;
}

// ---------- LayerNorm over 64 ch: f32 [b][c][hw] -> bf16 chunked [8][PXN][8] ----------
__global__ __launch_bounds__(256, 2)
void ln_px(const float* __restrict__ x, const float* __restrict__ w,
           const float* __restrict__ bia, bf16* __restrict__ out) {
    int idx = blockIdx.x * 256 + threadIdx.x;
    int b = idx >> 16, p = idx & 65535;
    const float* xp = x + (size_t)b * 64 * HWn + p;
    float f[64];
    float s = 0.f;
#pragma unroll
    for (int c = 0; c < 64; c++) { f[c] = xp[(size_t)c * HWn]; s += f[c]; }
    float mu = s * (1.f / 64.f);
    float s2 = 0.f;
#pragma unroll
    for (int c = 0; c < 64; c++) { float d = f[c] - mu; s2 += d * d; }
    float inv = rsqrtf(s2 * (1.f / 64.f) + 1e-5f);
#pragma unroll
    for (int c8 = 0; c8 < 8; c8++) {
        short8 o;
#pragma unroll
        for (int e = 0; e < 8; e++) {
            int c = c8 * 8 + e;
            o[e] = f2b((f[c] - mu) * inv * w[c] + bia[c]);
        }
        *reinterpret_cast<short8*>(out + ((size_t)c8 * PXN + idx) * 8) = o;
    }
}

// ---------- 1x1 conv via MFMA, chunked in/out. Wave loops over strips (B reused) ----------
__global__ __launch_bounds__(256)
void conv1x1_mfma(const bf16* __restrict__ in, const float* __restrict__ w,
                  int nstrips, int remap, bf16* __restrict__ out) {
    int lane = threadIdx.x & 63, wid = threadIdx.x >> 6;
    int r16 = lane & 15, grp = lane >> 4;
    size_t px0 = (size_t)blockIdx.x * 64;
    const bf16* bp0 = in + ((size_t)grp * PXN + px0 + r16) * 8;
    const bf16* bp1 = in + (((size_t)grp + 4) * PXN + px0 + r16) * 8;
    short8 b0[4], b1[4];
#pragma unroll
    for (int s = 0; s < 4; s++) {
        b0[s] = *reinterpret_cast<const short8*>(bp0 + s * 128);
        b1[s] = *reinterpret_cast<const short8*>(bp1 + s * 128);
    }
    for (int si = wid; si < nstrips; si += 4) {
        int co = si * 16 + r16;
        int row = co;
        if (remap) row = co < 170 ? co : (co >= 176 && co < 346 ? co - 6 : -1);
        short8 a0, a1;
        if (row >= 0) {
            const float* wr = w + (size_t)row * 64 + grp * 8;
#pragma unroll
            for (int e = 0; e < 8; e++) { a0[e] = f2b(wr[e]); a1[e] = f2b(wr[32 + e]); }
        } else {
            zero8(a0); zero8(a1);
        }
        int ochunk = si * 2 + (grp >> 1);
        int osub = (grp & 1) * 4;
#pragma unroll
        for (int s = 0; s < 4; s++) {
            f32x4 acc = {0.f, 0.f, 0.f, 0.f};
            acc = __builtin_amdgcn_mfma_f32_16x16x32_bf16(a0, b0[s], acc, 0, 0, 0);
            acc = __builtin_amdgcn_mfma_f32_16x16x32_bf16(a1, b1[s], acc, 0, 0, 0);
            size_t px = px0 + s * 16 + r16;
            s16x4 o;
#pragma unroll
            for (int j = 0; j < 4; j++) o[j] = f2b(acc[j]);
            *reinterpret_cast<s16x4*>(out + ((size_t)ochunk * PXN + px) * 8 + osub) = o;
        }
    }
}

// ---------- depthwise 3x3 over chunk span [c0, c0+nch), both tensors ----------
__global__ __launch_bounds__(256, 4)
void dwconv_span(const bf16* __restrict__ inx, const bf16* __restrict__ iny,
                 const float* __restrict__ w, int c0,
                 bf16* __restrict__ outx, bf16* __restrict__ outy) {
    int cid = blockIdx.x >> 7;
    int rb = blockIdx.x & 127;          // 4 rows each
    int chunk = c0 + cid;
    const bf16* in = blockIdx.y ? iny : inx;
    bf16* out = blockIdx.y ? outy : outx;
    int t = threadIdx.x;
    float wv[72];
#pragma unroll
    for (int i = 0; i < 72; i++) wv[i] = rfl(w[chunk * 72 + i]);
    int b = rb >> 6;
    int y0 = (rb & 63) * 4;
    const bf16* base = in + ((size_t)chunk * PXN + (size_t)b * 65536) * 8;
    bf16* obase = out + ((size_t)cid * PXN + (size_t)b * 65536) * 8;
    float acc[4][8];
    dw_quad(base, y0, t, wv, acc);
#pragma unroll
    for (int r = 0; r < 4; r++) {
        short8 o;
#pragma unroll
        for (int e = 0; e < 8; e++) o[e] = f2b(acc[r][e]);
        *reinterpret_cast<short8*>(obase + ((size_t)(y0 + r) * 256 + t) * 8) = o;
    }
}

// ---------- attention dots + row norms (chunked q/k buffers: q=chunk h, k=chunk 8+h) ----------
__global__ __launch_bounds__(256, 2)
void attn_dots_px(const bf16* __restrict__ qkx, const bf16* __restrict__ qky,
                  float* __restrict__ G, float* __restrict__ NA,
                  float* __restrict__ NB) {
    int which = blockIdx.z;
    int bh = blockIdx.y;
    int b = bh >> 3, h = bh & 7;
    const bf16* Aq = (which == 0 ? qky : qkx) + ((size_t)h * PXN + (size_t)b * 65536) * 8;
    const bf16* Bk = (which == 0 ? qkx : qky) + (((size_t)8 + h) * PXN + (size_t)b * 65536) * 8;
    float acc[8][8], na[8], nb[8];
#pragma unroll
    for (int c = 0; c < 8; c++) {
        na[c] = 0.f; nb[c] = 0.f;
#pragma unroll
        for (int d = 0; d < 8; d++) acc[c][d] = 0.f;
    }
    int per = 65536 / gridDim.x;
    int n0 = blockIdx.x * per;
    for (int n = n0 + threadIdx.x; n < n0 + per; n += 256) {
        short8 q8 = *reinterpret_cast<const short8*>(Aq + (size_t)n * 8);
        short8 k8 = *reinterpret_cast<const short8*>(Bk + (size_t)n * 8);
        float av[8], bv[8];
#pragma unroll
        for (int i = 0; i < 8; i++) { av[i] = b2f(q8[i]); bv[i] = b2f(k8[i]); }
#pragma unroll
        for (int c = 0; c < 8; c++) na[c] = fmaf(av[c], av[c], na[c]);
#pragma unroll
        for (int d = 0; d < 8; d++) nb[d] = fmaf(bv[d], bv[d], nb[d]);
#pragma unroll
        for (int c = 0; c < 8; c++)
#pragma unroll
            for (int d = 0; d < 8; d++) acc[c][d] = fmaf(av[c], bv[d], acc[c][d]);
    }
    size_t gbase = (((size_t)which * Bb + b) * 8 + h);
    float* Gp = G + gbase * 64;
#pragma unroll
    for (int c = 0; c < 8; c++)
#pragma unroll
        for (int d = 0; d < 8; d++) {
            float s = acc[c][d];
#pragma unroll
            for (int m = 1; m < 64; m <<= 1) s += __shfl_xor(s, m);
            if ((threadIdx.x & 63) == 0) atomicAdd(&Gp[c * 8 + d], s);
        }
#pragma unroll
    for (int c = 0; c < 8; c++) {
        float s = na[c];
#pragma unroll
        for (int m = 1; m < 64; m <<= 1) s += __shfl_xor(s, m);
        if ((threadIdx.x & 63) == 0) atomicAdd(&NA[gbase * 8 + c], s);
        float s2 = nb[c];
#pragma unroll
        for (int m = 1; m < 64; m <<= 1) s2 += __shfl_xor(s2, m);
        if ((threadIdx.x & 63) == 0) atomicAdd(&NB[gbase * 8 + c], s2);
    }
}

// ---------- tiny softmax with l2norm scaling and temperature ----------
__global__ void attn_softmax(const float* __restrict__ G, const float* __restrict__ NA,
                             const float* __restrict__ NB, const float* __restrict__ temp,
                             float* __restrict__ A) {
    int t = threadIdx.x;
    int h = (t >> 3) & 7;
    int c = t & 7;
    size_t rbase = t >> 3;
    const float* Gp = G + rbase * 64 + c * 8;
    float an = fmaxf(sqrtf(NA[rbase * 8 + c]), 1e-12f);
    float tm = temp[h];
    float vals[8];
    float mx = -1e30f;
#pragma unroll
    for (int d = 0; d < 8; d++) {
        float bn = fmaxf(sqrtf(NB[rbase * 8 + d]), 1e-12f);
        float v = Gp[d] / (an * bn) * tm;
        vals[d] = v;
        mx = fmaxf(mx, v);
    }
    float se = 0.f;
#pragma unroll
    for (int d = 0; d < 8; d++) { vals[d] = expf(vals[d] - mx); se += vals[d]; }
    float inv = 1.f / se;
    float* Ap = A + rbase * 64 + c * 8;
#pragma unroll
    for (int d = 0; d < 8; d++) Ap[d] = vals[d] * inv;
}

// ---------- cross attention + residual + LN2 (v in 8-chunk buffers) ----------
__global__ __launch_bounds__(256, 2)
void cross_ln2_px(const float* __restrict__ x, const bf16* __restrict__ vx,
                  const bf16* __restrict__ vy, const float* __restrict__ A,
                  const float* __restrict__ ln2w, const float* __restrict__ ln2b,
                  float* __restrict__ out, bf16* __restrict__ xn2) {
    int idx = blockIdx.x * 256 + threadIdx.x;
    int b = idx >> 16, p = idx & 65535;
    __shared__ float a1[512], a2[512];
    for (int i = threadIdx.x; i < 512; i += 256) {
        a1[i] = A[(size_t)b * 512 + i];
        a2[i] = A[((size_t)2 + b) * 512 + i];
    }
    __syncthreads();
    float o[64];
    const float* xp = x + (size_t)b * 64 * HWn + p;
#pragma unroll
    for (int c = 0; c < 64; c++) o[c] = xp[(size_t)c * HWn];
#pragma unroll
    for (int h = 0; h < 8; h++) {
        short8 v8 = *reinterpret_cast<const short8*>(vx + ((size_t)h * PXN + idx) * 8);
        short8 w8 = *reinterpret_cast<const short8*>(vy + ((size_t)h * PXN + idx) * 8);
        float v[8], v1[8];
#pragma unroll
        for (int d = 0; d < 8; d++) { v[d] = b2f(v8[d]); v1[d] = b2f(w8[d]); }
#pragma unroll
        for (int ci = 0; ci < 8; ci++) {
            float s = 0.f;
            const float* r1 = a1 + h * 64 + ci * 8;
            const float* r2 = a2 + h * 64 + ci * 8;
#pragma unroll
            for (int d = 0; d < 8; d++) s += r1[d] * v[d] + r2[d] * v1[d];
            o[h * 8 + ci] += s;
        }
    }
    float* op = out + (size_t)b * 64 * HWn + p;
    float s = 0.f;
#pragma unroll
    for (int c = 0; c < 64; c++) { op[(size_t)c * HWn] = o[c]; s += o[c]; }
    float mu = s * (1.f / 64.f);
    float s2 = 0.f;
#pragma unroll
    for (int c = 0; c < 64; c++) { float d = o[c] - mu; s2 += d * d; }
    float inv = rsqrtf(s2 * (1.f / 64.f) + 1e-5f);
#pragma unroll
    for (int c8 = 0; c8 < 8; c8++) {
        short8 o8;
#pragma unroll
        for (int e = 0; e < 8; e++) {
            int c = c8 * 8 + e;
            o8[e] = f2b((o[c] - mu) * inv * ln2w[c] + ln2b[c]);
        }
        *reinterpret_cast<short8*>(xn2 + ((size_t)c8 * PXN + idx) * 8) = o8;
    }
}

// ---------- fused GDFN dwconv + gelu gate: g(44 chunks) -> t(22 chunks) ----------
__global__ __launch_bounds__(256, 4)
void dwconv_gate(const bf16* __restrict__ g, const float* __restrict__ w,
                 bf16* __restrict__ tout) {
    int c = blockIdx.x >> 7;            // 0..21
    int rb = blockIdx.x & 127;          // 4 rows each
    int t = threadIdx.x;
    int b = rb >> 6;
    int y0 = (rb & 63) * 4;
    float wv[72];
#pragma unroll
    for (int i = 0; i < 72; i++)
        wv[i] = (c * 8 + i / 9 < 170) ? rfl(w[c * 72 + i]) : 0.f;
    const bf16* base1 = g + ((size_t)c * PXN + (size_t)b * 65536) * 8;
    float a1[4][8];
    dw_quad(base1, y0, t, wv, a1);
#pragma unroll
    for (int i = 0; i < 72; i++)
        wv[i] = (c * 8 + i / 9 < 170) ? rfl(w[(170 + c * 8) * 9 + i]) : 0.f;
    const bf16* base2 = g + (((size_t)22 + c) * PXN + (size_t)b * 65536) * 8;
    float a2[4][8];
    dw_quad(base2, y0, t, wv, a2);
    bf16* obase = tout + ((size_t)c * PXN + (size_t)b * 65536) * 8;
#pragma unroll
    for (int r = 0; r < 4; r++) {
        short8 o;
#pragma unroll
        for (int e = 0; e < 8; e++)
            o[e] = f2b(gelu_f(a1[r][e]) * a2[r][e]);
        *reinterpret_cast<short8*>(obase + ((size_t)(y0 + r) * 256 + t) * 8) = o;
    }
}

// ---------- GDFN out: MFMA 170(pad176)->64, B-frags direct from chunked t, += out ----------
__global__ __launch_bounds__(256, 4)
void gdfn_out_mfma(const bf16* __restrict__ t, const float* __restrict__ wout,
                   float* __restrict__ out) {
    int lane = threadIdx.x & 63, wid = threadIdx.x >> 6;
    int r16 = lane & 15, grp = lane >> 4;
    size_t px0 = (size_t)blockIdx.x * 64;
    int co = wid * 16 + r16;
    short8 af[6];
#pragma unroll
    for (int kc = 0; kc < 6; kc++) {
#pragma unroll
        for (int e = 0; e < 8; e++) {
            int k = kc * 32 + grp * 8 + e;
            af[kc][e] = (k < 170) ? f2b(wout[(size_t)co * 170 + k]) : (short)0;
        }
    }
#pragma unroll
    for (int s = 0; s < 4; s++) {
        size_t px = px0 + s * 16 + r16;
        f32x4 acc = {0.f, 0.f, 0.f, 0.f};
#pragma unroll
        for (int kc = 0; kc < 6; kc++) {
            int cidx = kc * 4 + grp;
            short8 bv;
            if (cidx < 22) bv = *reinterpret_cast<const short8*>(t + ((size_t)cidx * PXN + px) * 8);
            else zero8(bv);
            acc = __builtin_amdgcn_mfma_f32_16x16x32_bf16(af[kc], bv, acc, 0, 0, 0);
        }
        int b = (int)(px >> 16);
        int p = (int)(px & 65535);
        float* op = out + (size_t)b * 64 * HWn + (size_t)(wid * 16 + grp * 4) * HWn + p;
#pragma unroll
        for (int j = 0; j < 4; j++) op[(size_t)j * HWn] += acc[j];
    }
}

extern "C" void kernel_launch(void* const* d_in, const int* in_sizes, int n_in,
                              void* d_out, int out_size, void* d_ws, size_t ws_size,
                              hipStream_t stream) {
    const float* x = (const float*)d_in[0];
    const float* y = (const float*)d_in[1];
    const float* ln11_w = (const float*)d_in[2];
    const float* ln11_b = (const float*)d_in[3];
    const float* ln12_w = (const float*)d_in[4];
    const float* ln12_b = (const float*)d_in[5];
    const float* ln2_w = (const float*)d_in[6];
    const float* ln2_b = (const float*)d_in[7];
    const float* qkv_w = (const float*)d_in[8];
    const float* qkv_dw = (const float*)d_in[9];
    const float* temp = (const float*)d_in[10];
    const float* gdfn_in_w = (const float*)d_in[11];
    const float* gdfn_dw = (const float*)d_in[12];
    const float* gdfn_out_w = (const float*)d_in[13];
    float* out = (float*)d_out;

    char* wsb = (char*)d_ws;
    float* G = (float*)wsb;            // 2048
    float* NA = G + 2048;              // 256
    float* NB = NA + 256;              // 256
    float* Amat = NB + 256;            // 2048
    bf16* hp = (bf16*)(wsb + 18944);
    // chunk = PXN*8 = 1,048,576 elems = 2 MB. Element offsets from hp:
    bf16* xn   = hp;                        // 8 chunks   [0, 8.39M)
    bf16* yn   = hp + (size_t)8388608;      // 8 chunks   [8.39M, 16.78M)
    bf16* qkx  = hp;                        // 16 chunks, overlays xn+yn (dead after conv1x1)
    bf16* tx   = hp + (size_t)16777216;     // 24 chunks  [16.78M, 41.94M)
    bf16* ty   = hp + (size_t)41943040;     // 24 chunks  [41.94M, 67.11M)
    bf16* qky  = hp + (size_t)67108864;     // 16 chunks  [67.11M, 83.89M)
    bf16* vx   = hp + (size_t)83886080;     // 8 chunks   [83.89M, 92.27M)
    bf16* vy   = hp + (size_t)92274688;     // 8 chunks   [92.27M, 100.66M)
    bf16* g    = hp + (size_t)16777216;     // 44 chunks, overlays tx/ty (dead after dwconvs)
    bf16* t    = hp + (size_t)67108864;     // 22 chunks, overlays qky/vx (dead after cross)
    bf16* xn2  = hp;                        // 8 chunks (overlays qkx, dead after dots)

    zero_k<<<1, 256, 0, stream>>>(G, 2560);

    ln_px<<<512, 256, 0, stream>>>(x, ln11_w, ln11_b, xn);
    ln_px<<<512, 256, 0, stream>>>(y, ln12_w, ln12_b, yn);

    conv1x1_mfma<<<2048, 256, 0, stream>>>(xn, qkv_w, 12, 0, tx);
    conv1x1_mfma<<<2048, 256, 0, stream>>>(yn, qkv_w, 12, 0, ty);

    dwconv_span<<<dim3(16 * 128, 2), 256, 0, stream>>>(tx, ty, qkv_dw, 0, qkx, qky);
    dwconv_span<<<dim3(8 * 128, 2), 256, 0, stream>>>(tx, ty, qkv_dw, 16, vx, vy);

    attn_dots_px<<<dim3(16, 16, 2), 256, 0, stream>>>(qkx, qky, G, NA, NB);
    attn_softmax<<<1, 256, 0, stream>>>(G, NA, NB, temp, Amat);

    cross_ln2_px<<<512, 256, 0, stream>>>(x, vx, vy, Amat, ln2_w, ln2_b, out, xn2);

    conv1x1_mfma<<<2048, 256, 0, stream>>>(xn2, gdfn_in_w, 22, 1, g);
    dwconv_gate<<<22 * 128, 256, 0, stream>>>(g, gdfn_dw, t);
    gdfn_out_mfma<<<2048, 256, 0, stream>>>(t, gdfn_out_w, out);
}

// Round 9
// 317.077 us; speedup vs baseline: 1.6246x; 1.6246x over previous
//
#include <hip/hip_runtime.h>
#include <hip/hip_bf16.h>
#include <math.h>

#define HWn 65536
#define Hh 256
#define Wd 256
#define Bb 2
#define Cc 64
#define NHh 8
#define HIDc 170
#define PXN 131072   // Bb * HWn

typedef __hip_bfloat16 bf16;
typedef __attribute__((ext_vector_type(8))) short short8;
typedef __attribute__((ext_vector_type(4))) short s16x4;
typedef __attribute__((ext_vector_type(4))) float f32x4;

__device__ inline float b2f(short u) {
    unsigned int x = ((unsigned int)(unsigned short)u) << 16;
    return __uint_as_float(x);
}
__device__ inline short f2b(float f) {
    __hip_bfloat16 h = __float2bfloat16(f);
    return *reinterpret_cast<short*>(&h);
}
__device__ __forceinline__ void zero8(short8& v) {
#pragma unroll
    for (int e = 0; e < 8; e++) v[e] = 0;
}
__device__ __forceinline__ float rfl(float x) {
    return __uint_as_float(__builtin_amdgcn_readfirstlane(__float_as_uint(x)));
}
// gelu via A&S 7.1.26 erf poly, |err| <= 1.5e-7 (exact at bf16 output)
__device__ __forceinline__ float gelu_f(float x) {
    float z = fabsf(x) * 0.70710678118654752f;
    float tt = __builtin_amdgcn_rcpf(fmaf(0.3275911f, z, 1.f));
    float p = tt * fmaf(tt, fmaf(tt, fmaf(tt, fmaf(tt, 1.061405429f, -1.453152027f),
                                          1.421413741f), -0.284496736f), 0.254829592f);
    float e = __expf(-z * z);
    float er = fmaf(-p, e, 1.f);
    er = copysignf(er, x);
    return 0.5f * x * (1.f + er);
}

// dwconv for one output px (lane-owned), 8 ch, weights wv[72].
// base points at the batch-image of this chunk ([256 rows][256 px][8ch]).
__device__ __forceinline__ void dw_row_f(const bf16* __restrict__ base, int y, int t,
                                         const float* wv, float acc[8]) {
#pragma unroll
    for (int e = 0; e < 8; e++) acc[e] = 0.f;
#pragma unroll
    for (int dy = 0; dy < 3; dy++) {
        int ys = y + dy - 1;
        if (ys < 0 || ys >= 256) continue;
        const bf16* rp = base + (size_t)ys * 2048 + (size_t)t * 8;
        short8 c8 = *reinterpret_cast<const short8*>(rp);
        short8 l8, r8;
        if (t > 0) l8 = *reinterpret_cast<const short8*>(rp - 8); else zero8(l8);
        if (t < 255) r8 = *reinterpret_cast<const short8*>(rp + 8); else zero8(r8);
#pragma unroll
        for (int e = 0; e < 8; e++)
            acc[e] += wv[e * 9 + dy * 3] * b2f(l8[e]) +
                      wv[e * 9 + dy * 3 + 1] * b2f(c8[e]) +
                      wv[e * 9 + dy * 3 + 2] * b2f(r8[e]);
    }
}

// ---------- zero small scratch ----------
__global__ void zero_k(float* p, int n) {
    for (int i = threadIdx.x; i < n; i += 256) p[i] = 0.f;
}

// ---------- LayerNorm over 64 ch: f32 [b][c][hw] -> bf16 chunked [8][PXN][8] ----------
__global__ __launch_bounds__(256, 2)
void ln_px(const float* __restrict__ x, const float* __restrict__ w,
           const float* __restrict__ bia, bf16* __restrict__ out) {
    int idx = blockIdx.x * 256 + threadIdx.x;
    int b = idx >> 16, p = idx & 65535;
    const float* xp = x + (size_t)b * 64 * HWn + p;
    float f[64];
    float s = 0.f;
#pragma unroll
    for (int c = 0; c < 64; c++) { f[c] = xp[(size_t)c * HWn]; s += f[c]; }
    float mu = s * (1.f / 64.f);
    float s2 = 0.f;
#pragma unroll
    for (int c = 0; c < 64; c++) { float d = f[c] - mu; s2 += d * d; }
    float inv = rsqrtf(s2 * (1.f / 64.f) + 1e-5f);
#pragma unroll
    for (int c8 = 0; c8 < 8; c8++) {
        short8 o;
#pragma unroll
        for (int e = 0; e < 8; e++) {
            int c = c8 * 8 + e;
            o[e] = f2b((f[c] - mu) * inv * w[c] + bia[c]);
        }
        *reinterpret_cast<short8*>(out + ((size_t)c8 * PXN + idx) * 8) = o;
    }
}

// ---------- 1x1 conv via MFMA, chunked in/out. Wave loops over strips (B reused) ----------
__global__ __launch_bounds__(256)
void conv1x1_mfma(const bf16* __restrict__ in, const float* __restrict__ w,
                  int nstrips, int remap, bf16* __restrict__ out) {
    int lane = threadIdx.x & 63, wid = threadIdx.x >> 6;
    int r16 = lane & 15, grp = lane >> 4;
    size_t px0 = (size_t)blockIdx.x * 64;
    const bf16* bp0 = in + ((size_t)grp * PXN + px0 + r16) * 8;
    const bf16* bp1 = in + (((size_t)grp + 4) * PXN + px0 + r16) * 8;
    short8 b0[4], b1[4];
#pragma unroll
    for (int s = 0; s < 4; s++) {
        b0[s] = *reinterpret_cast<const short8*>(bp0 + s * 128);
        b1[s] = *reinterpret_cast<const short8*>(bp1 + s * 128);
    }
    for (int si = wid; si < nstrips; si += 4) {
        int co = si * 16 + r16;
        int row = co;
        if (remap) row = co < 170 ? co : (co >= 176 && co < 346 ? co - 6 : -1);
        short8 a0, a1;
        if (row >= 0) {
            const float* wr = w + (size_t)row * 64 + grp * 8;
#pragma unroll
            for (int e = 0; e < 8; e++) { a0[e] = f2b(wr[e]); a1[e] = f2b(wr[32 + e]); }
        } else {
            zero8(a0); zero8(a1);
        }
        int ochunk = si * 2 + (grp >> 1);
        int osub = (grp & 1) * 4;
#pragma unroll
        for (int s = 0; s < 4; s++) {
            f32x4 acc = {0.f, 0.f, 0.f, 0.f};
            acc = __builtin_amdgcn_mfma_f32_16x16x32_bf16(a0, b0[s], acc, 0, 0, 0);
            acc = __builtin_amdgcn_mfma_f32_16x16x32_bf16(a1, b1[s], acc, 0, 0, 0);
            size_t px = px0 + s * 16 + r16;
            s16x4 o;
#pragma unroll
            for (int j = 0; j < 4; j++) o[j] = f2b(acc[j]);
            *reinterpret_cast<s16x4*>(out + ((size_t)ochunk * PXN + px) * 8 + osub) = o;
        }
    }
}

// ---------- depthwise 3x3 over chunk span [c0, c0+nch) for both tensors ----------
// out chunk index = (chunk - c0). grid: (nch*128, 2); 4 rows per block.
__global__ __launch_bounds__(256, 4)
void dwconv_span(const bf16* __restrict__ inx, const bf16* __restrict__ iny,
                 const float* __restrict__ w, int c0,
                 bf16* __restrict__ outx, bf16* __restrict__ outy) {
    int cid = blockIdx.x >> 7;
    int rb = blockIdx.x & 127;          // 4 rows each
    int chunk = c0 + cid;
    const bf16* in = blockIdx.y ? iny : inx;
    bf16* out = blockIdx.y ? outy : outx;
    int t = threadIdx.x;
    float wv[72];
#pragma unroll
    for (int i = 0; i < 72; i++) wv[i] = w[chunk * 72 + i];
    int b = rb >> 6;
    const bf16* base = in + ((size_t)chunk * PXN + (size_t)b * 65536) * 8;
    bf16* obase = out + ((size_t)cid * PXN + (size_t)b * 65536) * 8;
#pragma unroll
    for (int r = 0; r < 4; r++) {
        int y = (rb * 4 + r) & 255;
        float acc[8];
        dw_row_f(base, y, t, wv, acc);
        short8 o;
#pragma unroll
        for (int e = 0; e < 8; e++) o[e] = f2b(acc[e]);
        *reinterpret_cast<short8*>(obase + ((size_t)y * 256 + t) * 8) = o;
    }
}

// ---------- attention dots + row norms (chunked q/k buffers: q=chunk h, k=chunk 8+h) ----------
__global__ __launch_bounds__(256, 2)
void attn_dots_px(const bf16* __restrict__ qkx, const bf16* __restrict__ qky,
                  float* __restrict__ G, float* __restrict__ NA,
                  float* __restrict__ NB) {
    int which = blockIdx.z;
    int bh = blockIdx.y;
    int b = bh >> 3, h = bh & 7;
    const bf16* Aq = (which == 0 ? qky : qkx) + ((size_t)h * PXN + (size_t)b * 65536) * 8;
    const bf16* Bk = (which == 0 ? qkx : qky) + (((size_t)8 + h) * PXN + (size_t)b * 65536) * 8;
    float acc[8][8], na[8], nb[8];
#pragma unroll
    for (int c = 0; c < 8; c++) {
        na[c] = 0.f; nb[c] = 0.f;
#pragma unroll
        for (int d = 0; d < 8; d++) acc[c][d] = 0.f;
    }
    int per = 65536 / gridDim.x;
    int n0 = blockIdx.x * per;
    for (int n = n0 + threadIdx.x; n < n0 + per; n += 256) {
        short8 q8 = *reinterpret_cast<const short8*>(Aq + (size_t)n * 8);
        short8 k8 = *reinterpret_cast<const short8*>(Bk + (size_t)n * 8);
        float av[8], bv[8];
#pragma unroll
        for (int i = 0; i < 8; i++) { av[i] = b2f(q8[i]); bv[i] = b2f(k8[i]); }
#pragma unroll
        for (int c = 0; c < 8; c++) na[c] = fmaf(av[c], av[c], na[c]);
#pragma unroll
        for (int d = 0; d < 8; d++) nb[d] = fmaf(bv[d], bv[d], nb[d]);
#pragma unroll
        for (int c = 0; c < 8; c++)
#pragma unroll
            for (int d = 0; d < 8; d++) acc[c][d] = fmaf(av[c], bv[d], acc[c][d]);
    }
    size_t gbase = (((size_t)which * Bb + b) * 8 + h);
    float* Gp = G + gbase * 64;
#pragma unroll
    for (int c = 0; c < 8; c++)
#pragma unroll
        for (int d = 0; d < 8; d++) {
            float s = acc[c][d];
#pragma unroll
            for (int m = 1; m < 64; m <<= 1) s += __shfl_xor(s, m);
            if ((threadIdx.x & 63) == 0) atomicAdd(&Gp[c * 8 + d], s);
        }
#pragma unroll
    for (int c = 0; c < 8; c++) {
        float s = na[c];
#pragma unroll
        for (int m = 1; m < 64; m <<= 1) s += __shfl_xor(s, m);
        if ((threadIdx.x & 63) == 0) atomicAdd(&NA[gbase * 8 + c], s);
        float s2 = nb[c];
#pragma unroll
        for (int m = 1; m < 64; m <<= 1) s2 += __shfl_xor(s2, m);
        if ((threadIdx.x & 63) == 0) atomicAdd(&NB[gbase * 8 + c], s2);
    }
}

// ---------- tiny softmax with l2norm scaling and temperature ----------
__global__ void attn_softmax(const float* __restrict__ G, const float* __restrict__ NA,
                             const float* __restrict__ NB, const float* __restrict__ temp,
                             float* __restrict__ A) {
    int t = threadIdx.x;
    int h = (t >> 3) & 7;
    int c = t & 7;
    size_t rbase = t >> 3;
    const float* Gp = G + rbase * 64 + c * 8;
    float an = fmaxf(sqrtf(NA[rbase * 8 + c]), 1e-12f);
    float tm = temp[h];
    float vals[8];
    float mx = -1e30f;
#pragma unroll
    for (int d = 0; d < 8; d++) {
        float bn = fmaxf(sqrtf(NB[rbase * 8 + d]), 1e-12f);
        float v = Gp[d] / (an * bn) * tm;
        vals[d] = v;
        mx = fmaxf(mx, v);
    }
    float se = 0.f;
#pragma unroll
    for (int d = 0; d < 8; d++) { vals[d] = expf(vals[d] - mx); se += vals[d]; }
    float inv = 1.f / se;
    float* Ap = A + rbase * 64 + c * 8;
#pragma unroll
    for (int d = 0; d < 8; d++) Ap[d] = vals[d] * inv;
}

// ---------- cross attention + residual + LN2 (v in 8-chunk buffers) ----------
__global__ __launch_bounds__(256, 2)
void cross_ln2_px(const float* __restrict__ x, const bf16* __restrict__ vx,
                  const bf16* __restrict__ vy, const float* __restrict__ A,
                  const float* __restrict__ ln2w, const float* __restrict__ ln2b,
                  float* __restrict__ out, bf16* __restrict__ xn2) {
    int idx = blockIdx.x * 256 + threadIdx.x;
    int b = idx >> 16, p = idx & 65535;
    __shared__ float a1[512], a2[512];
    for (int i = threadIdx.x; i < 512; i += 256) {
        a1[i] = A[(size_t)b * 512 + i];
        a2[i] = A[((size_t)2 + b) * 512 + i];
    }
    __syncthreads();
    float o[64];
    const float* xp = x + (size_t)b * 64 * HWn + p;
#pragma unroll
    for (int c = 0; c < 64; c++) o[c] = xp[(size_t)c * HWn];
#pragma unroll
    for (int h = 0; h < 8; h++) {
        short8 v8 = *reinterpret_cast<const short8*>(vx + ((size_t)h * PXN + idx) * 8);
        short8 w8 = *reinterpret_cast<const short8*>(vy + ((size_t)h * PXN + idx) * 8);
        float v[8], v1[8];
#pragma unroll
        for (int d = 0; d < 8; d++) { v[d] = b2f(v8[d]); v1[d] = b2f(w8[d]); }
#pragma unroll
        for (int ci = 0; ci < 8; ci++) {
            float s = 0.f;
            const float* r1 = a1 + h * 64 + ci * 8;
            const float* r2 = a2 + h * 64 + ci * 8;
#pragma unroll
            for (int d = 0; d < 8; d++) s += r1[d] * v[d] + r2[d] * v1[d];
            o[h * 8 + ci] += s;
        }
    }
    float* op = out + (size_t)b * 64 * HWn + p;
    float s = 0.f;
#pragma unroll
    for (int c = 0; c < 64; c++) { op[(size_t)c * HWn] = o[c]; s += o[c]; }
    float mu = s * (1.f / 64.f);
    float s2 = 0.f;
#pragma unroll
    for (int c = 0; c < 64; c++) { float d = o[c] - mu; s2 += d * d; }
    float inv = rsqrtf(s2 * (1.f / 64.f) + 1e-5f);
#pragma unroll
    for (int c8 = 0; c8 < 8; c8++) {
        short8 o8;
#pragma unroll
        for (int e = 0; e < 8; e++) {
            int c = c8 * 8 + e;
            o8[e] = f2b((o[c] - mu) * inv * ln2w[c] + ln2b[c]);
        }
        *reinterpret_cast<short8*>(xn2 + ((size_t)c8 * PXN + idx) * 8) = o8;
    }
}

// ---------- fused GDFN dwconv + gelu gate: g(44 chunks) -> t(22 chunks) ----------
__global__ __launch_bounds__(256, 3)
void dwconv_gate(const bf16* __restrict__ g, const float* __restrict__ w,
                 bf16* __restrict__ tout) {
    int c = blockIdx.x >> 7;            // 0..21
    int rb = blockIdx.x & 127;          // 4 rows each
    int t = threadIdx.x;
    int b = rb >> 6;
    float wv[72];
#pragma unroll
    for (int i = 0; i < 72; i++)
        wv[i] = (c * 8 + i / 9 < 170) ? rfl(w[c * 72 + i]) : 0.f;
    const bf16* base1 = g + ((size_t)c * PXN + (size_t)b * 65536) * 8;
    float a1r[4][8];
#pragma unroll
    for (int r = 0; r < 4; r++) {
        int y = (rb * 4 + r) & 255;
        dw_row_f(base1, y, t, wv, a1r[r]);
    }
#pragma unroll
    for (int i = 0; i < 72; i++)
        wv[i] = (c * 8 + i / 9 < 170) ? rfl(w[(170 + c * 8) * 9 + i]) : 0.f;
    const bf16* base2 = g + (((size_t)22 + c) * PXN + (size_t)b * 65536) * 8;
    bf16* obase = tout + ((size_t)c * PXN + (size_t)b * 65536) * 8;
#pragma unroll
    for (int r = 0; r < 4; r++) {
        int y = (rb * 4 + r) & 255;
        float a2[8];
        dw_row_f(base2, y, t, wv, a2);
        short8 o;
#pragma unroll
        for (int e = 0; e < 8; e++)
            o[e] = f2b(gelu_f(a1r[r][e]) * a2[e]);
        *reinterpret_cast<short8*>(obase + ((size_t)y * 256 + t) * 8) = o;
    }
}

// ---------- GDFN out: MFMA 170(pad176)->64, B-frags direct from chunked t, += out ----------
__global__ __launch_bounds__(256, 4)
void gdfn_out_mfma(const bf16* __restrict__ t, const float* __restrict__ wout,
                   float* __restrict__ out) {
    int lane = threadIdx.x & 63, wid = threadIdx.x >> 6;
    int r16 = lane & 15, grp = lane >> 4;
    size_t px0 = (size_t)blockIdx.x * 64;
    int co = wid * 16 + r16;
    short8 af[6];
#pragma unroll
    for (int kc = 0; kc < 6; kc++) {
#pragma unroll
        for (int e = 0; e < 8; e++) {
            int k = kc * 32 + grp * 8 + e;
            af[kc][e] = (k < 170) ? f2b(wout[(size_t)co * 170 + k]) : (short)0;
        }
    }
#pragma unroll
    for (int s = 0; s < 4; s++) {
        size_t px = px0 + s * 16 + r16;
        f32x4 acc = {0.f, 0.f, 0.f, 0.f};
#pragma unroll
        for (int kc = 0; kc < 6; kc++) {
            int cidx = kc * 4 + grp;
            short8 bv;
            if (cidx < 22) bv = *reinterpret_cast<const short8*>(t + ((size_t)cidx * PXN + px) * 8);
            else zero8(bv);
            acc = __builtin_amdgcn_mfma_f32_16x16x32_bf16(af[kc], bv, acc, 0, 0, 0);
        }
        int b = (int)(px >> 16);
        int p = (int)(px & 65535);
        float* op = out + (size_t)b * 64 * HWn + (size_t)(wid * 16 + grp * 4) * HWn + p;
#pragma unroll
        for (int j = 0; j < 4; j++) op[(size_t)j * HWn] += acc[j];
    }
}

extern "C" void kernel_launch(void* const* d_in, const int* in_sizes, int n_in,
                              void* d_out, int out_size, void* d_ws, size_t ws_size,
                              hipStream_t stream) {
    const float* x = (const float*)d_in[0];
    const float* y = (const float*)d_in[1];
    const float* ln11_w = (const float*)d_in[2];
    const float* ln11_b = (const float*)d_in[3];
    const float* ln12_w = (const float*)d_in[4];
    const float* ln12_b = (const float*)d_in[5];
    const float* ln2_w = (const float*)d_in[6];
    const float* ln2_b = (const float*)d_in[7];
    const float* qkv_w = (const float*)d_in[8];
    const float* qkv_dw = (const float*)d_in[9];
    const float* temp = (const float*)d_in[10];
    const float* gdfn_in_w = (const float*)d_in[11];
    const float* gdfn_dw = (const float*)d_in[12];
    const float* gdfn_out_w = (const float*)d_in[13];
    float* out = (float*)d_out;

    char* wsb = (char*)d_ws;
    float* G = (float*)wsb;            // 2048
    float* NA = G + 2048;              // 256
    float* NB = NA + 256;              // 256
    float* Amat = NB + 256;            // 2048
    bf16* hp = (bf16*)(wsb + 18944);
    // chunk = PXN*8 = 1,048,576 elems = 2 MB. Element offsets from hp:
    bf16* xn   = hp;                        // 8 chunks   [0, 8.39M)
    bf16* yn   = hp + (size_t)8388608;      // 8 chunks   [8.39M, 16.78M)
    bf16* qkx  = hp;                        // 16 chunks, overlays xn+yn (dead after conv1x1)
    bf16* tx   = hp + (size_t)16777216;     // 24 chunks  [16.78M, 41.94M)
    bf16* ty   = hp + (size_t)41943040;     // 24 chunks  [41.94M, 67.11M)
    bf16* qky  = hp + (size_t)67108864;     // 16 chunks  [67.11M, 83.89M)
    bf16* vx   = hp + (size_t)83886080;     // 8 chunks   [83.89M, 92.27M)
    bf16* vy   = hp + (size_t)92274688;     // 8 chunks   [92.27M, 100.66M)
    bf16* g    = hp + (size_t)16777216;     // 44 chunks, overlays tx/ty (dead after dwconvs)
    bf16* t    = hp + (size_t)67108864;     // 22 chunks, overlays qky/vx (dead after cross)
    bf16* xn2  = hp;                        // 8 chunks (overlays qkx, dead after dots)

    zero_k<<<1, 256, 0, stream>>>(G, 2560);

    ln_px<<<512, 256, 0, stream>>>(x, ln11_w, ln11_b, xn);
    ln_px<<<512, 256, 0, stream>>>(y, ln12_w, ln12_b, yn);

    conv1x1_mfma<<<2048, 256, 0, stream>>>(xn, qkv_w, 12, 0, tx);
    conv1x1_mfma<<<2048, 256, 0, stream>>>(yn, qkv_w, 12, 0, ty);

    dwconv_span<<<dim3(16 * 128, 2), 256, 0, stream>>>(tx, ty, qkv_dw, 0, qkx, qky);
    dwconv_span<<<dim3(8 * 128, 2), 256, 0, stream>>>(tx, ty, qkv_dw, 16, vx, vy);

    attn_dots_px<<<dim3(16, 16, 2), 256, 0, stream>>>(qkx, qky, G, NA, NB);
    attn_softmax<<<1, 256, 0, stream>>>(G, NA, NB, temp, Amat);

    cross_ln2_px<<<512, 256, 0, stream>>>(x, vx, vy, Amat, ln2_w, ln2_b, out, xn2);

    conv1x1_mfma<<<2048, 256, 0, stream>>>(xn2, gdfn_in_w, 22, 1, g);
    dwconv_gate<<<22 * 128, 256, 0, stream>>>(g, gdfn_dw, t);
    gdfn_out_mfma<<<2048, 256, 0, stream>>>(t, gdfn_out_w, out);
}